// Round 6
// baseline (1182.421 us; speedup 1.0000x reference)
//
#include <hip/hip_runtime.h>
#include <math.h>

#define HDIM 128
#define NGAUSS 50
#define NLAYER 6

typedef unsigned short ushortT;
typedef __attribute__((ext_vector_type(8))) short bf16x8;
typedef __attribute__((ext_vector_type(4))) float f32x4;

static __device__ __forceinline__ float bf2f(unsigned short u){
  union { unsigned int i; float f; } x; x.i = ((unsigned int)u) << 16; return x.f;
}
static __device__ __forceinline__ unsigned short f2bf(float f){
  union { float f; unsigned int i; } x; x.f = f;
  unsigned int i = x.i;
  unsigned int r = (i + 0x7FFFu + ((i >> 16) & 1u)) >> 16;
  return (unsigned short)r;
}
// softplus(x) - log(2), numerically stable
static __device__ __forceinline__ float ssp(float x){
  float sp = fmaxf(x, 0.0f) + log1pf(expf(-fabsf(x)));
  return sp - 0.69314718055994530942f;
}

// ---------------- CSR build ----------------
__global__ void k_count(const int* __restrict__ row, int* __restrict__ counts, int E){
  int e = blockIdx.x * 256 + threadIdx.x;
  if (e < E) atomicAdd(&counts[row[e]], 1);
}

// 3-phase decoupled scan: blockSums -> scan blockSums -> per-block scan+offset
__global__ void k_scan1(const int* __restrict__ counts, int* __restrict__ blockSums, int N){
  __shared__ int red[256];
  int tid = threadIdx.x;
  int i = blockIdx.x * 256 + tid;
  red[tid] = (i < N) ? counts[i] : 0;
  __syncthreads();
  #pragma unroll
  for (int off = 128; off > 0; off >>= 1){
    if (tid < off) red[tid] += red[tid + off];
    __syncthreads();
  }
  if (tid == 0) blockSums[blockIdx.x] = red[0];
}

__global__ void k_scan2(const int* __restrict__ blockSums, int* __restrict__ blockOff, int nb){
  __shared__ int s[1024];
  int tid = threadIdx.x;
  s[tid] = (tid < nb) ? blockSums[tid] : 0;
  __syncthreads();
  for (int off = 1; off < 1024; off <<= 1){
    int t = (tid >= off) ? s[tid - off] : 0;
    __syncthreads();
    s[tid] += t;
    __syncthreads();
  }
  if (tid < nb) blockOff[tid] = (tid == 0) ? 0 : s[tid - 1];
}

__global__ void k_scan3(const int* __restrict__ counts, const int* __restrict__ blockOff,
                        int* __restrict__ offsets, int* __restrict__ cursor, int N){
  __shared__ int s[256];
  int tid = threadIdx.x;
  int i = blockIdx.x * 256 + tid;
  int v = (i < N) ? counts[i] : 0;
  s[tid] = v;
  __syncthreads();
  #pragma unroll
  for (int off = 1; off < 256; off <<= 1){
    int t = (tid >= off) ? s[tid - off] : 0;
    __syncthreads();
    s[tid] += t;
    __syncthreads();
  }
  int excl = blockOff[blockIdx.x] + s[tid] - v;
  if (i < N){ offsets[i] = excl; cursor[i] = excl; }
  if (i == N - 1) offsets[N] = excl + v;
}

// csr record: (col, dist-bits) packed as int2 -> one 8B store, one 8B load
__global__ void k_fill(const int* __restrict__ row, const int* __restrict__ col,
                       const float* __restrict__ pos, int* __restrict__ cursor,
                       int2* __restrict__ csr_cd, int E){
  int e = blockIdx.x * 256 + threadIdx.x;
  if (e >= E) return;
  int r = row[e], c = col[e];
  float dx = pos[r*3+0] - pos[c*3+0];
  float dy = pos[r*3+1] - pos[c*3+1];
  float dz = pos[r*3+2] - pos[c*3+2];
  float d = sqrtf(dx*dx + dy*dy + dz*dz);
  int slot = atomicAdd(&cursor[r], 1);
  csr_cd[slot] = make_int2(c, __float_as_int(d));
}

// ---------------- init / precompute ----------------
__global__ void k_init_v(const int* __restrict__ z, const float* __restrict__ emb,
                         ushortT* __restrict__ vhi, ushortT* __restrict__ vlo, int N){
  int idx = blockIdx.x * 256 + threadIdx.x;
  if (idx >= N * HDIM) return;
  int n = idx >> 7, f = idx & 127;
  float w = emb[z[n] * HDIM + f];
  unsigned short hi = f2bf(w);
  vhi[idx] = hi;
  vlo[idx] = f2bf(w - bf2f(hi));
}

// transpose + split weights: dst[mat][n][k] (hi/lo bf16) from src[mat][k][n] (f32)
__global__ void k_prepw(const float* __restrict__ W, ushortT* __restrict__ Whi,
                        ushortT* __restrict__ Wlo, int total){
  int idx = blockIdx.x * 256 + threadIdx.x;
  if (idx >= total) return;
  int mat = idx >> 14;           // / (128*128)
  int rem = idx & 16383;
  int n = rem >> 7, k = rem & 127;
  float w = W[(mat << 14) + k * HDIM + n];
  unsigned short hi = f2bf(w);
  Whi[idx] = hi;
  Wlo[idx] = f2bf(w - bf2f(hi));
}

// a[l][f] = sum_g dist_W[g]*We[l][g][f];  c[l][f] = sum_g dist_b[g]*We[l][g][f] + be[l][f]
__global__ void k_ac(const float* __restrict__ dW, const float* __restrict__ db,
                     const float* __restrict__ We, const float* __restrict__ be,
                     float* __restrict__ a, float* __restrict__ c){
  int idx = blockIdx.x * 256 + threadIdx.x;
  if (idx >= NLAYER * HDIM) return;
  int l = idx >> 7, f = idx & 127;
  float av = 0.f, cv = 0.f;
  for (int g = 0; g < NGAUSS; ++g){
    float we = We[(l * NGAUSS + g) * HDIM + f];
    av += dW[g] * we;
    cv += db[g] * we;
  }
  a[idx] = av;
  c[idx] = cv + be[idx];
}

// ---------------- 128x128 GEMM via MFMA, split precision, B from L2 ----------
// No LDS: the 128KB hi+lo weight working set is L2-resident and shared by all
// blocks. One 16-row tile per wave; B fragments are 16B/lane global loads
// (16 ncols x 64B = fully-utilized 1KB wave transactions).
// MODE 0: out = X @ W             -> outHi (bf16, hi only; feeds the gather)
// MODE 1: out = ssp(X @ W + b)    -> outHi/outLo (bf16 hi+lo split)
template<int MODE>
__global__ __launch_bounds__(256, 4)
void k_gemm(const ushortT* __restrict__ Xhi, const ushortT* __restrict__ Xlo,
            const ushortT* __restrict__ WhiT, const ushortT* __restrict__ WloT,
            const float* __restrict__ bias,
            ushortT* __restrict__ outHi, ushortT* __restrict__ outLo, int N){
  int tid = threadIdx.x;
  int wave = tid >> 6, lane = tid & 63;
  int m = lane & 15, quad = lane >> 4;
  int ntiles = (N + 15) >> 4;
  int tile = blockIdx.x * 4 + wave;
  if (tile >= ntiles) return;
  int rowBase = tile << 4;
  int row = rowBase + m; if (row >= N) row = N - 1;

  bf16x8 ahi[4], alo[4];
  #pragma unroll
  for (int kk = 0; kk < 4; ++kk){
    ahi[kk] = *(const bf16x8*)(Xhi + ((size_t)row << 7) + kk*32 + quad*8);
    alo[kk] = *(const bf16x8*)(Xlo + ((size_t)row << 7) + kk*32 + quad*8);
  }

  #pragma unroll
  for (int ct = 0; ct < 8; ++ct){
    int ncol = ct * 16 + m;
    const ushortT* bph = WhiT + ((size_t)ncol << 7) + quad*8;
    const ushortT* bpl = WloT + ((size_t)ncol << 7) + quad*8;
    bf16x8 bh0 = *(const bf16x8*)(bph);
    bf16x8 bh1 = *(const bf16x8*)(bph + 32);
    bf16x8 bh2 = *(const bf16x8*)(bph + 64);
    bf16x8 bh3 = *(const bf16x8*)(bph + 96);
    bf16x8 bl0 = *(const bf16x8*)(bpl);
    bf16x8 bl1 = *(const bf16x8*)(bpl + 32);
    bf16x8 bl2 = *(const bf16x8*)(bpl + 64);
    bf16x8 bl3 = *(const bf16x8*)(bpl + 96);
    f32x4 d = {0.f, 0.f, 0.f, 0.f};
    d = __builtin_amdgcn_mfma_f32_16x16x32_bf16(ahi[0], bh0, d, 0, 0, 0);
    d = __builtin_amdgcn_mfma_f32_16x16x32_bf16(ahi[1], bh1, d, 0, 0, 0);
    d = __builtin_amdgcn_mfma_f32_16x16x32_bf16(ahi[2], bh2, d, 0, 0, 0);
    d = __builtin_amdgcn_mfma_f32_16x16x32_bf16(ahi[3], bh3, d, 0, 0, 0);
    d = __builtin_amdgcn_mfma_f32_16x16x32_bf16(ahi[0], bl0, d, 0, 0, 0);
    d = __builtin_amdgcn_mfma_f32_16x16x32_bf16(ahi[1], bl1, d, 0, 0, 0);
    d = __builtin_amdgcn_mfma_f32_16x16x32_bf16(ahi[2], bl2, d, 0, 0, 0);
    d = __builtin_amdgcn_mfma_f32_16x16x32_bf16(ahi[3], bl3, d, 0, 0, 0);
    d = __builtin_amdgcn_mfma_f32_16x16x32_bf16(alo[0], bh0, d, 0, 0, 0);
    d = __builtin_amdgcn_mfma_f32_16x16x32_bf16(alo[1], bh1, d, 0, 0, 0);
    d = __builtin_amdgcn_mfma_f32_16x16x32_bf16(alo[2], bh2, d, 0, 0, 0);
    d = __builtin_amdgcn_mfma_f32_16x16x32_bf16(alo[3], bh3, d, 0, 0, 0);
    #pragma unroll
    for (int r = 0; r < 4; ++r){
      int orow = rowBase + quad*4 + r;
      if (orow < N){
        if (MODE == 0){
          outHi[((size_t)orow << 7) + ncol] = f2bf(d[r]);
        } else {
          float s = ssp(d[r] + bias[ncol]);
          unsigned short hi = f2bf(s);
          outHi[((size_t)orow << 7) + ncol] = hi;
          outLo[((size_t)orow << 7) + ncol] = f2bf(s - bf2f(hi));
        }
      }
    }
  }
}

// ---------------- edge aggregation: one wave per node, bf16 h, 8-edge MLP ----
__global__ void k_agg(const ushortT* __restrict__ h, const int* __restrict__ offsets,
                      const int2* __restrict__ cd, const float* __restrict__ a,
                      const float* __restrict__ c,
                      ushortT* __restrict__ aggHi, ushortT* __restrict__ aggLo, int N){
  int node = blockIdx.x * 4 + (threadIdx.x >> 6);
  if (node >= N) return;
  int lane = threadIdx.x & 63;
  int f = lane * 2;                       // this lane covers features f, f+1
  float a0 = a[f], a1 = a[f+1], c0 = c[f], c1 = c[f+1];
  int s = offsets[node], e = offsets[node + 1];
  float acc0 = 0.f, acc1 = 0.f;
  int j = s;
  // peel one edge if start is odd so int4 loads below are 16B-aligned
  if ((j & 1) && j < e){
    int2 q = cd[j];
    unsigned int p = *(const unsigned int*)(h + ((size_t)q.x << 7) + f);
    float dd = __int_as_float(q.y);
    acc0 = fmaf(bf2f((ushortT)p),          fmaf(dd, a0, c0), acc0);
    acc1 = fmaf(bf2f((ushortT)(p >> 16)),  fmaf(dd, a1, c1), acc1);
    ++j;
  }
  for (; j + 8 <= e; j += 8){
    int4 qa = *(const int4*)(cd + j);       // edges j, j+1
    int4 qb = *(const int4*)(cd + j + 2);
    int4 qc = *(const int4*)(cd + j + 4);
    int4 qd = *(const int4*)(cd + j + 6);
    unsigned int p0 = *(const unsigned int*)(h + ((size_t)qa.x << 7) + f);
    unsigned int p1 = *(const unsigned int*)(h + ((size_t)qa.z << 7) + f);
    unsigned int p2 = *(const unsigned int*)(h + ((size_t)qb.x << 7) + f);
    unsigned int p3 = *(const unsigned int*)(h + ((size_t)qb.z << 7) + f);
    unsigned int p4 = *(const unsigned int*)(h + ((size_t)qc.x << 7) + f);
    unsigned int p5 = *(const unsigned int*)(h + ((size_t)qc.z << 7) + f);
    unsigned int p6 = *(const unsigned int*)(h + ((size_t)qd.x << 7) + f);
    unsigned int p7 = *(const unsigned int*)(h + ((size_t)qd.z << 7) + f);
    float d0 = __int_as_float(qa.y), d1 = __int_as_float(qa.w);
    float d2 = __int_as_float(qb.y), d3 = __int_as_float(qb.w);
    float d4 = __int_as_float(qc.y), d5 = __int_as_float(qc.w);
    float d6 = __int_as_float(qd.y), d7 = __int_as_float(qd.w);
    acc0 = fmaf(bf2f((ushortT)p0),         fmaf(d0, a0, c0), acc0);
    acc1 = fmaf(bf2f((ushortT)(p0 >> 16)), fmaf(d0, a1, c1), acc1);
    acc0 = fmaf(bf2f((ushortT)p1),         fmaf(d1, a0, c0), acc0);
    acc1 = fmaf(bf2f((ushortT)(p1 >> 16)), fmaf(d1, a1, c1), acc1);
    acc0 = fmaf(bf2f((ushortT)p2),         fmaf(d2, a0, c0), acc0);
    acc1 = fmaf(bf2f((ushortT)(p2 >> 16)), fmaf(d2, a1, c1), acc1);
    acc0 = fmaf(bf2f((ushortT)p3),         fmaf(d3, a0, c0), acc0);
    acc1 = fmaf(bf2f((ushortT)(p3 >> 16)), fmaf(d3, a1, c1), acc1);
    acc0 = fmaf(bf2f((ushortT)p4),         fmaf(d4, a0, c0), acc0);
    acc1 = fmaf(bf2f((ushortT)(p4 >> 16)), fmaf(d4, a1, c1), acc1);
    acc0 = fmaf(bf2f((ushortT)p5),         fmaf(d5, a0, c0), acc0);
    acc1 = fmaf(bf2f((ushortT)(p5 >> 16)), fmaf(d5, a1, c1), acc1);
    acc0 = fmaf(bf2f((ushortT)p6),         fmaf(d6, a0, c0), acc0);
    acc1 = fmaf(bf2f((ushortT)(p6 >> 16)), fmaf(d6, a1, c1), acc1);
    acc0 = fmaf(bf2f((ushortT)p7),         fmaf(d7, a0, c0), acc0);
    acc1 = fmaf(bf2f((ushortT)(p7 >> 16)), fmaf(d7, a1, c1), acc1);
  }
  for (; j < e; ++j){
    int2 q = cd[j];
    unsigned int p = *(const unsigned int*)(h + ((size_t)q.x << 7) + f);
    float dd = __int_as_float(q.y);
    acc0 = fmaf(bf2f((ushortT)p),         fmaf(dd, a0, c0), acc0);
    acc1 = fmaf(bf2f((ushortT)(p >> 16)), fmaf(dd, a1, c1), acc1);
  }
  unsigned short h0 = f2bf(acc0), h1 = f2bf(acc1);
  size_t o = ((size_t)node << 7) + f;
  *(unsigned int*)(aggHi + o) = (unsigned int)h0 | ((unsigned int)h1 << 16);
  unsigned short l0 = f2bf(acc0 - bf2f(h0)), l1 = f2bf(acc1 - bf2f(h1));
  *(unsigned int*)(aggLo + o) = (unsigned int)l0 | ((unsigned int)l1 << 16);
}

// ---------------- readout: one wave per node, writes u[node] (no atomics) ----
__global__ void k_readout(const ushortT* __restrict__ vhi, const ushortT* __restrict__ vlo,
                          const float* __restrict__ W1, const float* __restrict__ b1,
                          const float* __restrict__ W2, const float* __restrict__ b2,
                          float* __restrict__ u, int N){
  __shared__ float vbuf[4][HDIM];
  int wave = threadIdx.x >> 6, lane = threadIdx.x & 63;
  int node = blockIdx.x * 4 + wave;
  if (node >= N) return;
  int f = lane * 2;
  unsigned int hh = *(const unsigned int*)(vhi + ((size_t)node << 7) + f);
  unsigned int ll = *(const unsigned int*)(vlo + ((size_t)node << 7) + f);
  vbuf[wave][f]     = bf2f((ushortT)hh)         + bf2f((ushortT)ll);
  vbuf[wave][f + 1] = bf2f((ushortT)(hh >> 16)) + bf2f((ushortT)(ll >> 16));
  float t0 = b1[lane], t1 = 0.f;        // split dependency chain
  #pragma unroll 8
  for (int k = 0; k < HDIM; k += 2){
    t0 = fmaf(vbuf[wave][k],     W1[k * 64 + lane],       t0);
    t1 = fmaf(vbuf[wave][k + 1], W1[(k + 1) * 64 + lane], t1);
  }
  float partial = ssp(t0 + t1) * W2[lane];
  #pragma unroll
  for (int off = 32; off > 0; off >>= 1)
    partial += __shfl_down(partial, off, 64);
  if (lane == 0)
    u[node] = partial + b2[0];
}

// ---------------- group segment sum over sorted batch ----------------
// groupOff[g] = first node index with batch >= g;  groupOff[G] = N
__global__ void k_bounds(const int* __restrict__ batch, int* __restrict__ groupOff,
                         int N, int G){
  int i = blockIdx.x * 256 + threadIdx.x;
  if (i >= N) return;
  int b = batch[i];
  if (i == 0){
    for (int g = 0; g <= b; ++g) groupOff[g] = 0;
  } else {
    int pb = batch[i - 1];
    for (int g = pb + 1; g <= b; ++g) groupOff[g] = i;
  }
  if (i == N - 1){
    for (int g = b + 1; g <= G; ++g) groupOff[g] = N;
  }
}

__global__ void k_gsum(const float* __restrict__ u, const int* __restrict__ groupOff,
                       float* __restrict__ out, int G){
  int g = blockIdx.x * 4 + (threadIdx.x >> 6);
  if (g >= G) return;
  int lane = threadIdx.x & 63;
  int s = groupOff[g], e = groupOff[g + 1];
  float acc = 0.f;
  for (int j = s + lane; j < e; j += 64) acc += u[j];
  #pragma unroll
  for (int off = 32; off > 0; off >>= 1)
    acc += __shfl_down(acc, off, 64);
  if (lane == 0) out[g] = acc;
}

extern "C" void kernel_launch(void* const* d_in, const int* in_sizes, int n_in,
                              void* d_out, int out_size, void* d_ws, size_t ws_size,
                              hipStream_t stream){
  const int N = in_sizes[0];
  const int E = in_sizes[3] / 2;
  const int G = out_size;

  const int*   z     = (const int*)d_in[0];
  const float* pos   = (const float*)d_in[1];
  const int*   batch = (const int*)d_in[2];
  const int*   eidx  = (const int*)d_in[3];
  const int*   erow  = eidx;
  const int*   ecol  = eidx + E;
  const float* emb   = (const float*)d_in[4];
  const float* dW    = (const float*)d_in[5];
  const float* db    = (const float*)d_in[6];
  const float* Wn    = (const float*)d_in[7];
  const float* We    = (const float*)d_in[8];
  const float* be    = (const float*)d_in[9];
  const float* Wo    = (const float*)d_in[10];
  const float* bo    = (const float*)d_in[11];
  const float* W1    = (const float*)d_in[12];
  const float* b1    = (const float*)d_in[13];
  const float* W2    = (const float*)d_in[14];
  const float* b2    = (const float*)d_in[15];

  char* ws = (char*)d_ws;
  size_t off = 0;
  auto alloc = [&](size_t bytes) -> char* {
    char* p = ws + off;
    off = (off + bytes + 255) & ~(size_t)255;
    return p;
  };
  int nscanb = (N + 255) / 256;
  int*     counts   = (int*)    alloc((size_t)N * 4);
  int*     offsets  = (int*)    alloc((size_t)(N + 1) * 4);
  int*     cursor   = (int*)    alloc((size_t)N * 4);
  int*     blockSums= (int*)    alloc((size_t)nscanb * 4);
  int*     blockOff = (int*)    alloc((size_t)nscanb * 4);
  int2*    csr_cd   = (int2*)   alloc((size_t)E * 8);
  ushortT* h        = (ushortT*)alloc((size_t)N * HDIM * 2);
  ushortT* vhi      = (ushortT*)alloc((size_t)N * HDIM * 2);
  ushortT* vlo      = (ushortT*)alloc((size_t)N * HDIM * 2);
  ushortT* agghi    = (ushortT*)alloc((size_t)N * HDIM * 2);
  ushortT* agglo    = (ushortT*)alloc((size_t)N * HDIM * 2);
  ushortT* WnHiT    = (ushortT*)alloc((size_t)NLAYER * HDIM * HDIM * 2);
  ushortT* WnLoT    = (ushortT*)alloc((size_t)NLAYER * HDIM * HDIM * 2);
  ushortT* WoHiT    = (ushortT*)alloc((size_t)NLAYER * HDIM * HDIM * 2);
  ushortT* WoLoT    = (ushortT*)alloc((size_t)NLAYER * HDIM * HDIM * 2);
  float*   a        = (float*)  alloc((size_t)NLAYER * HDIM * 4);
  float*   c        = (float*)  alloc((size_t)NLAYER * HDIM * 4);
  float*   u        = (float*)  alloc((size_t)N * 4);
  int*     groupOff = (int*)    alloc((size_t)(G + 1) * 4);

  hipMemsetAsync(counts, 0, (size_t)N * 4, stream);

  k_count<<<(E + 255) / 256, 256, 0, stream>>>(erow, counts, E);
  k_scan1<<<nscanb, 256, 0, stream>>>(counts, blockSums, N);
  k_scan2<<<1, 1024, 0, stream>>>(blockSums, blockOff, nscanb);
  k_scan3<<<nscanb, 256, 0, stream>>>(counts, blockOff, offsets, cursor, N);
  k_fill<<<(E + 255) / 256, 256, 0, stream>>>(erow, ecol, pos, cursor, csr_cd, E);
  k_init_v<<<((size_t)N * HDIM + 255) / 256, 256, 0, stream>>>(z, emb, vhi, vlo, N);
  int wtotal = NLAYER * HDIM * HDIM;
  k_prepw<<<(wtotal + 255) / 256, 256, 0, stream>>>(Wn, WnHiT, WnLoT, wtotal);
  k_prepw<<<(wtotal + 255) / 256, 256, 0, stream>>>(Wo, WoHiT, WoLoT, wtotal);
  k_ac<<<(NLAYER * HDIM + 255) / 256, 256, 0, stream>>>(dW, db, We, be, a, c);
  k_bounds<<<(N + 255) / 256, 256, 0, stream>>>(batch, groupOff, N, G);

  int ntiles = (N + 15) >> 4;
  int gemmGrid = (ntiles + 3) / 4;        // 4 waves/block, 1 tile/wave
  int nodeGrid = (N + 3) / 4;
  for (int l = 0; l < NLAYER; ++l){
    size_t wo = (size_t)l * HDIM * HDIM;
    k_gemm<0><<<gemmGrid, 256, 0, stream>>>(vhi, vlo, WnHiT + wo, WnLoT + wo,
                                            nullptr, h, nullptr, N);
    k_agg<<<nodeGrid, 256, 0, stream>>>(h, offsets, csr_cd,
                                        a + l * HDIM, c + l * HDIM, agghi, agglo, N);
    k_gemm<1><<<gemmGrid, 256, 0, stream>>>(agghi, agglo, WoHiT + wo, WoLoT + wo,
                                            bo + (size_t)l * HDIM, vhi, vlo, N);
  }
  k_readout<<<nodeGrid, 256, 0, stream>>>(vhi, vlo, W1, b1, W2, b2, u, N);
  k_gsum<<<(G + 3) / 4, 256, 0, stream>>>(u, groupOff, (float*)d_out, G);
}

// Round 7
// 1077.007 us; speedup vs baseline: 1.0979x; 1.0979x over previous
//
#include <hip/hip_runtime.h>
#include <math.h>

#define HDIM 128
#define NGAUSS 50
#define NLAYER 6
#define TSTR 136   // LDS tile row stride in shorts; %8==0 keeps ds_read_b128 16B-aligned

typedef unsigned short ushortT;
typedef __attribute__((ext_vector_type(8))) short bf16x8;
typedef __attribute__((ext_vector_type(4))) float f32x4;

static __device__ __forceinline__ float bf2f(unsigned short u){
  union { unsigned int i; float f; } x; x.i = ((unsigned int)u) << 16; return x.f;
}
static __device__ __forceinline__ unsigned short f2bf(float f){
  union { float f; unsigned int i; } x; x.f = f;
  unsigned int i = x.i;
  unsigned int r = (i + 0x7FFFu + ((i >> 16) & 1u)) >> 16;
  return (unsigned short)r;
}
// softplus(x) - log(2), numerically stable
static __device__ __forceinline__ float ssp(float x){
  float sp = fmaxf(x, 0.0f) + log1pf(expf(-fabsf(x)));
  return sp - 0.69314718055994530942f;
}

// ---------------- CSR build ----------------
__global__ void k_count(const int* __restrict__ row, int* __restrict__ counts, int E){
  int e = blockIdx.x * 256 + threadIdx.x;
  if (e < E) atomicAdd(&counts[row[e]], 1);
}

// 3-phase decoupled scan
__global__ void k_scan1(const int* __restrict__ counts, int* __restrict__ blockSums, int N){
  __shared__ int red[256];
  int tid = threadIdx.x;
  int i = blockIdx.x * 256 + tid;
  red[tid] = (i < N) ? counts[i] : 0;
  __syncthreads();
  #pragma unroll
  for (int off = 128; off > 0; off >>= 1){
    if (tid < off) red[tid] += red[tid + off];
    __syncthreads();
  }
  if (tid == 0) blockSums[blockIdx.x] = red[0];
}

__global__ void k_scan2(const int* __restrict__ blockSums, int* __restrict__ blockOff, int nb){
  __shared__ int s[1024];
  int tid = threadIdx.x;
  s[tid] = (tid < nb) ? blockSums[tid] : 0;
  __syncthreads();
  for (int off = 1; off < 1024; off <<= 1){
    int t = (tid >= off) ? s[tid - off] : 0;
    __syncthreads();
    s[tid] += t;
    __syncthreads();
  }
  if (tid < nb) blockOff[tid] = (tid == 0) ? 0 : s[tid - 1];
}

__global__ void k_scan3(const int* __restrict__ counts, const int* __restrict__ blockOff,
                        int* __restrict__ offsets, int* __restrict__ cursor, int N){
  __shared__ int s[256];
  int tid = threadIdx.x;
  int i = blockIdx.x * 256 + tid;
  int v = (i < N) ? counts[i] : 0;
  s[tid] = v;
  __syncthreads();
  #pragma unroll
  for (int off = 1; off < 256; off <<= 1){
    int t = (tid >= off) ? s[tid - off] : 0;
    __syncthreads();
    s[tid] += t;
    __syncthreads();
  }
  int excl = blockOff[blockIdx.x] + s[tid] - v;
  if (i < N){ offsets[i] = excl; cursor[i] = excl; }
  if (i == N - 1) offsets[N] = excl + v;
}

// csr record: (col, dist-bits) packed as int2
__global__ void k_fill(const int* __restrict__ row, const int* __restrict__ col,
                       const float* __restrict__ pos, int* __restrict__ cursor,
                       int2* __restrict__ csr_cd, int E){
  int e = blockIdx.x * 256 + threadIdx.x;
  if (e >= E) return;
  int r = row[e], c = col[e];
  float dx = pos[r*3+0] - pos[c*3+0];
  float dy = pos[r*3+1] - pos[c*3+1];
  float dz = pos[r*3+2] - pos[c*3+2];
  float d = sqrtf(dx*dx + dy*dy + dz*dz);
  int slot = atomicAdd(&cursor[r], 1);
  csr_cd[slot] = make_int2(c, __float_as_int(d));
}

// ---------------- init / precompute ----------------
__global__ void k_init_v(const int* __restrict__ z, const float* __restrict__ emb,
                         ushortT* __restrict__ vhi, ushortT* __restrict__ vlo, int N){
  int idx = blockIdx.x * 256 + threadIdx.x;
  if (idx >= N * HDIM) return;
  int n = idx >> 7, f = idx & 127;
  float w = emb[z[n] * HDIM + f];
  unsigned short hi = f2bf(w);
  vhi[idx] = hi;
  vlo[idx] = f2bf(w - bf2f(hi));
}

// transpose + split weights: dst[mat][n][k] (hi/lo bf16) from src[mat][k][n] (f32)
__global__ void k_prepw(const float* __restrict__ W, ushortT* __restrict__ Whi,
                        ushortT* __restrict__ Wlo, int total){
  int idx = blockIdx.x * 256 + threadIdx.x;
  if (idx >= total) return;
  int mat = idx >> 14;
  int rem = idx & 16383;
  int n = rem >> 7, k = rem & 127;
  float w = W[(mat << 14) + k * HDIM + n];
  unsigned short hi = f2bf(w);
  Whi[idx] = hi;
  Wlo[idx] = f2bf(w - bf2f(hi));
}

__global__ void k_ac(const float* __restrict__ dW, const float* __restrict__ db,
                     const float* __restrict__ We, const float* __restrict__ be,
                     float* __restrict__ a, float* __restrict__ c){
  int idx = blockIdx.x * 256 + threadIdx.x;
  if (idx >= NLAYER * HDIM) return;
  int l = idx >> 7, f = idx & 127;
  float av = 0.f, cv = 0.f;
  for (int g = 0; g < NGAUSS; ++g){
    float we = We[(l * NGAUSS + g) * HDIM + f];
    av += dW[g] * we;
    cv += db[g] * we;
  }
  a[idx] = av;
  c[idx] = cv + be[idx];
}

// 12-MFMA split-precision product accumulate: d += X(hi/lo) @ B(hi/lo)
static __device__ __forceinline__ f32x4 mfma12(const bf16x8* ahi, const bf16x8* alo,
                                               const ushortT* bph, const ushortT* bpl){
  bf16x8 bh0 = *(const bf16x8*)(bph);
  bf16x8 bh1 = *(const bf16x8*)(bph + 32);
  bf16x8 bh2 = *(const bf16x8*)(bph + 64);
  bf16x8 bh3 = *(const bf16x8*)(bph + 96);
  bf16x8 bl0 = *(const bf16x8*)(bpl);
  bf16x8 bl1 = *(const bf16x8*)(bpl + 32);
  bf16x8 bl2 = *(const bf16x8*)(bpl + 64);
  bf16x8 bl3 = *(const bf16x8*)(bpl + 96);
  f32x4 d = {0.f, 0.f, 0.f, 0.f};
  d = __builtin_amdgcn_mfma_f32_16x16x32_bf16(ahi[0], bh0, d, 0, 0, 0);
  d = __builtin_amdgcn_mfma_f32_16x16x32_bf16(ahi[1], bh1, d, 0, 0, 0);
  d = __builtin_amdgcn_mfma_f32_16x16x32_bf16(ahi[2], bh2, d, 0, 0, 0);
  d = __builtin_amdgcn_mfma_f32_16x16x32_bf16(ahi[3], bh3, d, 0, 0, 0);
  d = __builtin_amdgcn_mfma_f32_16x16x32_bf16(ahi[0], bl0, d, 0, 0, 0);
  d = __builtin_amdgcn_mfma_f32_16x16x32_bf16(ahi[1], bl1, d, 0, 0, 0);
  d = __builtin_amdgcn_mfma_f32_16x16x32_bf16(ahi[2], bl2, d, 0, 0, 0);
  d = __builtin_amdgcn_mfma_f32_16x16x32_bf16(ahi[3], bl3, d, 0, 0, 0);
  d = __builtin_amdgcn_mfma_f32_16x16x32_bf16(alo[0], bh0, d, 0, 0, 0);
  d = __builtin_amdgcn_mfma_f32_16x16x32_bf16(alo[1], bh1, d, 0, 0, 0);
  d = __builtin_amdgcn_mfma_f32_16x16x32_bf16(alo[2], bh2, d, 0, 0, 0);
  d = __builtin_amdgcn_mfma_f32_16x16x32_bf16(alo[3], bh3, d, 0, 0, 0);
  return d;
}

// ---------------- initial GEMM: h = v0 @ Wn[0], bf16-hi output ----------------
__global__ __launch_bounds__(256, 4)
void k_gemm0(const ushortT* __restrict__ Xhi, const ushortT* __restrict__ Xlo,
             const ushortT* __restrict__ WhiT, const ushortT* __restrict__ WloT,
             ushortT* __restrict__ outHi, int N){
  int tid = threadIdx.x;
  int wave = tid >> 6, lane = tid & 63;
  int m = lane & 15, quad = lane >> 4;
  int ntiles = (N + 15) >> 4;
  int tile = blockIdx.x * 4 + wave;
  if (tile >= ntiles) return;
  int rowBase = tile << 4;
  int row = rowBase + m; if (row >= N) row = N - 1;

  bf16x8 ahi[4], alo[4];
  #pragma unroll
  for (int kk = 0; kk < 4; ++kk){
    ahi[kk] = *(const bf16x8*)(Xhi + ((size_t)row << 7) + kk*32 + quad*8);
    alo[kk] = *(const bf16x8*)(Xlo + ((size_t)row << 7) + kk*32 + quad*8);
  }
  #pragma unroll
  for (int ct = 0; ct < 8; ++ct){
    int ncol = ct * 16 + m;
    f32x4 d = mfma12(ahi, alo, WhiT + ((size_t)ncol << 7) + quad*8,
                               WloT + ((size_t)ncol << 7) + quad*8);
    #pragma unroll
    for (int r = 0; r < 4; ++r){
      int orow = rowBase + quad*4 + r;
      if (orow < N) outHi[((size_t)orow << 7) + ncol] = f2bf(d[r]);
    }
  }
}

// ---------------- fused: v = ssp(agg@Wo+bo); then (if !LAST) h = v@WnNext ----
// Each wave owns its private 16x128 LDS tile (stride TSTR) -> no __syncthreads.
template<int LAST>
__global__ __launch_bounds__(256, 3)
void k_fused(const ushortT* __restrict__ aggHi, const ushortT* __restrict__ aggLo,
             const ushortT* __restrict__ WoHiT, const ushortT* __restrict__ WoLoT,
             const float* __restrict__ bo,
             const ushortT* __restrict__ WnHiT, const ushortT* __restrict__ WnLoT,
             ushortT* __restrict__ outH,
             ushortT* __restrict__ vhi, ushortT* __restrict__ vlo, int N){
  __shared__ ushortT th[4][16 * TSTR];
  __shared__ ushortT tl[4][16 * TSTR];
  int tid = threadIdx.x;
  int wave = tid >> 6, lane = tid & 63;
  int m = lane & 15, quad = lane >> 4;
  int ntiles = (N + 15) >> 4;
  int tile = blockIdx.x * 4 + wave;
  if (tile >= ntiles) return;
  int rowBase = tile << 4;
  int row = rowBase + m; if (row >= N) row = N - 1;

  bf16x8 ahi[4], alo[4];
  #pragma unroll
  for (int kk = 0; kk < 4; ++kk){
    ahi[kk] = *(const bf16x8*)(aggHi + ((size_t)row << 7) + kk*32 + quad*8);
    alo[kk] = *(const bf16x8*)(aggLo + ((size_t)row << 7) + kk*32 + quad*8);
  }
  #pragma unroll
  for (int ct = 0; ct < 8; ++ct){
    int ncol = ct * 16 + m;
    f32x4 d = mfma12(ahi, alo, WoHiT + ((size_t)ncol << 7) + quad*8,
                               WoLoT + ((size_t)ncol << 7) + quad*8);
    float bb = bo[ncol];
    #pragma unroll
    for (int r = 0; r < 4; ++r){
      float s = ssp(d[r] + bb);
      unsigned short hi = f2bf(s);
      unsigned short lo = f2bf(s - bf2f(hi));
      if (LAST){
        int orow = rowBase + quad*4 + r;
        if (orow < N){
          vhi[((size_t)orow << 7) + ncol] = hi;
          vlo[((size_t)orow << 7) + ncol] = lo;
        }
      } else {
        int idx = (quad*4 + r) * TSTR + ncol;
        th[wave][idx] = hi;
        tl[wave][idx] = lo;
      }
    }
  }
  if (!LAST){
    // same-wave LDS write->read dependency; compiler orders via lgkmcnt
    bf16x8 ahi2[4], alo2[4];
    #pragma unroll
    for (int kk = 0; kk < 4; ++kk){
      ahi2[kk] = *(const bf16x8*)(&th[wave][m * TSTR + kk*32 + quad*8]);
      alo2[kk] = *(const bf16x8*)(&tl[wave][m * TSTR + kk*32 + quad*8]);
    }
    #pragma unroll
    for (int ct = 0; ct < 8; ++ct){
      int ncol = ct * 16 + m;
      f32x4 d = mfma12(ahi2, alo2, WnHiT + ((size_t)ncol << 7) + quad*8,
                                   WnLoT + ((size_t)ncol << 7) + quad*8);
      #pragma unroll
      for (int r = 0; r < 4; ++r){
        int orow = rowBase + quad*4 + r;
        if (orow < N) outH[((size_t)orow << 7) + ncol] = f2bf(d[r]);
      }
    }
  }
}

// ---------------- edge aggregation: one wave per node, bf16 h, 16-deep MLP ----
__global__ __launch_bounds__(256, 4)
void k_agg(const ushortT* __restrict__ h, const int* __restrict__ offsets,
           const int2* __restrict__ cd, const float* __restrict__ a,
           const float* __restrict__ c,
           ushortT* __restrict__ aggHi, ushortT* __restrict__ aggLo, int N){
  int node = blockIdx.x * 4 + (threadIdx.x >> 6);
  if (node >= N) return;
  int lane = threadIdx.x & 63;
  int f = lane * 2;
  float a0 = a[f], a1 = a[f+1], c0 = c[f], c1 = c[f+1];
  int s = offsets[node], e = offsets[node + 1];
  float acc0 = 0.f, acc1 = 0.f;
  int j = s;
  if ((j & 1) && j < e){            // align to int4
    int2 q = cd[j];
    unsigned int p = *(const unsigned int*)(h + ((size_t)q.x << 7) + f);
    float dd = __int_as_float(q.y);
    acc0 = fmaf(bf2f((ushortT)p),          fmaf(dd, a0, c0), acc0);
    acc1 = fmaf(bf2f((ushortT)(p >> 16)),  fmaf(dd, a1, c1), acc1);
    ++j;
  }
  for (; j + 16 <= e; j += 16){
    int4 q[8];
    #pragma unroll
    for (int i = 0; i < 8; ++i) q[i] = *(const int4*)(cd + j + 2*i);
    unsigned int p[16];
    #pragma unroll
    for (int i = 0; i < 8; ++i){
      p[2*i]   = *(const unsigned int*)(h + ((size_t)q[i].x << 7) + f);
      p[2*i+1] = *(const unsigned int*)(h + ((size_t)q[i].z << 7) + f);
    }
    #pragma unroll
    for (int i = 0; i < 8; ++i){
      float d0 = __int_as_float(q[i].y), d1 = __int_as_float(q[i].w);
      acc0 = fmaf(bf2f((ushortT)p[2*i]),           fmaf(d0, a0, c0), acc0);
      acc1 = fmaf(bf2f((ushortT)(p[2*i]   >> 16)), fmaf(d0, a1, c1), acc1);
      acc0 = fmaf(bf2f((ushortT)p[2*i+1]),         fmaf(d1, a0, c0), acc0);
      acc1 = fmaf(bf2f((ushortT)(p[2*i+1] >> 16)), fmaf(d1, a1, c1), acc1);
    }
  }
  for (; j + 2 <= e; j += 2){
    int4 q = *(const int4*)(cd + j);
    unsigned int p0 = *(const unsigned int*)(h + ((size_t)q.x << 7) + f);
    unsigned int p1 = *(const unsigned int*)(h + ((size_t)q.z << 7) + f);
    float d0 = __int_as_float(q.y), d1 = __int_as_float(q.w);
    acc0 = fmaf(bf2f((ushortT)p0),         fmaf(d0, a0, c0), acc0);
    acc1 = fmaf(bf2f((ushortT)(p0 >> 16)), fmaf(d0, a1, c1), acc1);
    acc0 = fmaf(bf2f((ushortT)p1),         fmaf(d1, a0, c0), acc0);
    acc1 = fmaf(bf2f((ushortT)(p1 >> 16)), fmaf(d1, a1, c1), acc1);
  }
  if (j < e){
    int2 q = cd[j];
    unsigned int p = *(const unsigned int*)(h + ((size_t)q.x << 7) + f);
    float dd = __int_as_float(q.y);
    acc0 = fmaf(bf2f((ushortT)p),         fmaf(dd, a0, c0), acc0);
    acc1 = fmaf(bf2f((ushortT)(p >> 16)), fmaf(dd, a1, c1), acc1);
  }
  unsigned short h0 = f2bf(acc0), h1 = f2bf(acc1);
  size_t o = ((size_t)node << 7) + f;
  *(unsigned int*)(aggHi + o) = (unsigned int)h0 | ((unsigned int)h1 << 16);
  unsigned short l0 = f2bf(acc0 - bf2f(h0)), l1 = f2bf(acc1 - bf2f(h1));
  *(unsigned int*)(aggLo + o) = (unsigned int)l0 | ((unsigned int)l1 << 16);
}

// ---------------- readout: one wave per node, writes u[node] ----------------
__global__ void k_readout(const ushortT* __restrict__ vhi, const ushortT* __restrict__ vlo,
                          const float* __restrict__ W1, const float* __restrict__ b1,
                          const float* __restrict__ W2, const float* __restrict__ b2,
                          float* __restrict__ u, int N){
  __shared__ float vbuf[4][HDIM];
  int wave = threadIdx.x >> 6, lane = threadIdx.x & 63;
  int node = blockIdx.x * 4 + wave;
  if (node >= N) return;
  int f = lane * 2;
  unsigned int hh = *(const unsigned int*)(vhi + ((size_t)node << 7) + f);
  unsigned int ll = *(const unsigned int*)(vlo + ((size_t)node << 7) + f);
  vbuf[wave][f]     = bf2f((ushortT)hh)         + bf2f((ushortT)ll);
  vbuf[wave][f + 1] = bf2f((ushortT)(hh >> 16)) + bf2f((ushortT)(ll >> 16));
  float t0 = b1[lane], t1 = 0.f;
  #pragma unroll 8
  for (int k = 0; k < HDIM; k += 2){
    t0 = fmaf(vbuf[wave][k],     W1[k * 64 + lane],       t0);
    t1 = fmaf(vbuf[wave][k + 1], W1[(k + 1) * 64 + lane], t1);
  }
  float partial = ssp(t0 + t1) * W2[lane];
  #pragma unroll
  for (int off = 32; off > 0; off >>= 1)
    partial += __shfl_down(partial, off, 64);
  if (lane == 0)
    u[node] = partial + b2[0];
}

// ---------------- group segment sum over sorted batch ----------------
__global__ void k_bounds(const int* __restrict__ batch, int* __restrict__ groupOff,
                         int N, int G){
  int i = blockIdx.x * 256 + threadIdx.x;
  if (i >= N) return;
  int b = batch[i];
  if (i == 0){
    for (int g = 0; g <= b; ++g) groupOff[g] = 0;
  } else {
    int pb = batch[i - 1];
    for (int g = pb + 1; g <= b; ++g) groupOff[g] = i;
  }
  if (i == N - 1){
    for (int g = b + 1; g <= G; ++g) groupOff[g] = N;
  }
}

__global__ void k_gsum(const float* __restrict__ u, const int* __restrict__ groupOff,
                       float* __restrict__ out, int G){
  int g = blockIdx.x * 4 + (threadIdx.x >> 6);
  if (g >= G) return;
  int lane = threadIdx.x & 63;
  int s = groupOff[g], e = groupOff[g + 1];
  float acc = 0.f;
  for (int j = s + lane; j < e; j += 64) acc += u[j];
  #pragma unroll
  for (int off = 32; off > 0; off >>= 1)
    acc += __shfl_down(acc, off, 64);
  if (lane == 0) out[g] = acc;
}

extern "C" void kernel_launch(void* const* d_in, const int* in_sizes, int n_in,
                              void* d_out, int out_size, void* d_ws, size_t ws_size,
                              hipStream_t stream){
  const int N = in_sizes[0];
  const int E = in_sizes[3] / 2;
  const int G = out_size;

  const int*   z     = (const int*)d_in[0];
  const float* pos   = (const float*)d_in[1];
  const int*   batch = (const int*)d_in[2];
  const int*   eidx  = (const int*)d_in[3];
  const int*   erow  = eidx;
  const int*   ecol  = eidx + E;
  const float* emb   = (const float*)d_in[4];
  const float* dW    = (const float*)d_in[5];
  const float* db    = (const float*)d_in[6];
  const float* Wn    = (const float*)d_in[7];
  const float* We    = (const float*)d_in[8];
  const float* be    = (const float*)d_in[9];
  const float* Wo    = (const float*)d_in[10];
  const float* bo    = (const float*)d_in[11];
  const float* W1    = (const float*)d_in[12];
  const float* b1    = (const float*)d_in[13];
  const float* W2    = (const float*)d_in[14];
  const float* b2    = (const float*)d_in[15];

  char* ws = (char*)d_ws;
  size_t off = 0;
  auto alloc = [&](size_t bytes) -> char* {
    char* p = ws + off;
    off = (off + bytes + 255) & ~(size_t)255;
    return p;
  };
  int nscanb = (N + 255) / 256;
  int*     counts   = (int*)    alloc((size_t)N * 4);
  int*     offsets  = (int*)    alloc((size_t)(N + 1) * 4);
  int*     cursor   = (int*)    alloc((size_t)N * 4);
  int*     blockSums= (int*)    alloc((size_t)nscanb * 4);
  int*     blockOff = (int*)    alloc((size_t)nscanb * 4);
  int2*    csr_cd   = (int2*)   alloc((size_t)E * 8);
  ushortT* h        = (ushortT*)alloc((size_t)N * HDIM * 2);
  ushortT* vhi      = (ushortT*)alloc((size_t)N * HDIM * 2);
  ushortT* vlo      = (ushortT*)alloc((size_t)N * HDIM * 2);
  ushortT* agghi    = (ushortT*)alloc((size_t)N * HDIM * 2);
  ushortT* agglo    = (ushortT*)alloc((size_t)N * HDIM * 2);
  ushortT* WnHiT    = (ushortT*)alloc((size_t)NLAYER * HDIM * HDIM * 2);
  ushortT* WnLoT    = (ushortT*)alloc((size_t)NLAYER * HDIM * HDIM * 2);
  ushortT* WoHiT    = (ushortT*)alloc((size_t)NLAYER * HDIM * HDIM * 2);
  ushortT* WoLoT    = (ushortT*)alloc((size_t)NLAYER * HDIM * HDIM * 2);
  float*   a        = (float*)  alloc((size_t)NLAYER * HDIM * 4);
  float*   c        = (float*)  alloc((size_t)NLAYER * HDIM * 4);
  float*   u        = (float*)  alloc((size_t)N * 4);
  int*     groupOff = (int*)    alloc((size_t)(G + 1) * 4);

  hipMemsetAsync(counts, 0, (size_t)N * 4, stream);

  k_count<<<(E + 255) / 256, 256, 0, stream>>>(erow, counts, E);
  k_scan1<<<nscanb, 256, 0, stream>>>(counts, blockSums, N);
  k_scan2<<<1, 1024, 0, stream>>>(blockSums, blockOff, nscanb);
  k_scan3<<<nscanb, 256, 0, stream>>>(counts, blockOff, offsets, cursor, N);
  k_fill<<<(E + 255) / 256, 256, 0, stream>>>(erow, ecol, pos, cursor, csr_cd, E);
  k_init_v<<<((size_t)N * HDIM + 255) / 256, 256, 0, stream>>>(z, emb, vhi, vlo, N);
  int wtotal = NLAYER * HDIM * HDIM;
  k_prepw<<<(wtotal + 255) / 256, 256, 0, stream>>>(Wn, WnHiT, WnLoT, wtotal);
  k_prepw<<<(wtotal + 255) / 256, 256, 0, stream>>>(Wo, WoHiT, WoLoT, wtotal);
  k_ac<<<(NLAYER * HDIM + 255) / 256, 256, 0, stream>>>(dW, db, We, be, a, c);
  k_bounds<<<(N + 255) / 256, 256, 0, stream>>>(batch, groupOff, N, G);

  int ntiles = (N + 15) >> 4;
  int gemmGrid = (ntiles + 3) / 4;        // 4 waves/block, 1 tile/wave
  int nodeGrid = (N + 3) / 4;

  // h = v0 @ Wn[0]
  k_gemm0<<<gemmGrid, 256, 0, stream>>>(vhi, vlo, WnHiT, WnLoT, h, N);
  for (int l = 0; l < NLAYER; ++l){
    size_t wo = (size_t)l * HDIM * HDIM;
    k_agg<<<nodeGrid, 256, 0, stream>>>(h, offsets, csr_cd,
                                        a + l * HDIM, c + l * HDIM, agghi, agglo, N);
    if (l < NLAYER - 1){
      size_t wn = (size_t)(l + 1) * HDIM * HDIM;
      k_fused<0><<<gemmGrid, 256, 0, stream>>>(agghi, agglo, WoHiT + wo, WoLoT + wo,
                                               bo + (size_t)l * HDIM,
                                               WnHiT + wn, WnLoT + wn,
                                               h, nullptr, nullptr, N);
    } else {
      k_fused<1><<<gemmGrid, 256, 0, stream>>>(agghi, agglo, WoHiT + wo, WoLoT + wo,
                                               bo + (size_t)l * HDIM,
                                               nullptr, nullptr,
                                               nullptr, vhi, vlo, N);
    }
  }
  k_readout<<<nodeGrid, 256, 0, stream>>>(vhi, vlo, W1, b1, W2, b2, u, N);
  k_gsum<<<(G + 3) / 4, 256, 0, stream>>>(u, groupOff, (float*)d_out, G);
}